// Round 5
// baseline (262140.186 us; speedup 1.0000x reference)
//
#include <hip/hip_runtime.h>
#include <stdint.h>
#include <stddef.h>

#define B 16
#define T 400
#define E 768
#define PDIM 256
#define H 1024
#define ADIM 128
#define LDIM 32
#define MDIM 80
#define GSZ 256           // persistent grid blocks (1/CU; resident even with half the CUs)
#define NZERO 145664      // 6*B*H + 2*B*E + B*H + B*T
#define NRPK 327680       // repacked postnet weight elems per array
#define NBAR 1024         // barrier state ints

typedef unsigned short u16;
typedef __attribute__((ext_vector_type(8))) short short8v;
typedef __attribute__((ext_vector_type(4))) float float4v;

__device__ __forceinline__ float bf2f(u16 u){
  union { uint32_t i; float f; } v; v.i = ((uint32_t)u) << 16; return v.f;
}
__device__ __forceinline__ u16 f2bf(float f){
  union { float f; uint32_t i; } v; v.f = f;
  uint32_t x = v.i;
  return (u16)((x + 0x7FFFu + ((x >> 16) & 1u)) >> 16);
}
__device__ __forceinline__ float fast_sig(float x){ return 1.f/(1.f+__expf(-x)); }
__device__ __forceinline__ float fast_tanh(float x){ float e=__expf(2.f*x); return 1.f - 2.f/(e+1.f); }

template<bool F32>
__device__ __forceinline__ float ld1(const void* p, size_t i){
  if constexpr(F32){ float v; __builtin_memcpy(&v, (const float*)p + i, 4); return v; }
  else { u16 h; __builtin_memcpy(&h, (const u16*)p + i, 2); return bf2f(h); }
}
template<bool F32>
__device__ __forceinline__ void ld4(const void* p, size_t i, float o[4]){
  if constexpr(F32){ __builtin_memcpy(o, (const float*)p + i, 16); }
  else {
    uint2 u; __builtin_memcpy(&u, (const u16*)p + i, 8);
    o[0]=bf2f((u16)(u.x & 0xffffu)); o[1]=bf2f((u16)(u.x >> 16));
    o[2]=bf2f((u16)(u.y & 0xffffu)); o[3]=bf2f((u16)(u.y >> 16));
  }
}
template<bool F32>
__device__ __forceinline__ void st1(void* p, size_t i, float v){
  if constexpr(F32) ((float*)p)[i] = v; else ((u16*)p)[i] = f2bf(v);
}

// ---------------- software grid barrier ----------------
// layout in bar[]: leaf counters at [l*16], l<32 (8 arrivals each);
// root counter at [512]; generation at [528].
__device__ __forceinline__ void gbar(int* bar){
  __syncthreads();
  __threadfence();                              // release our writes
  if(threadIdx.x == 0){
    int* gen = bar + 528;
    int g = __atomic_load_n(gen, __ATOMIC_RELAXED);
    int leaf = (blockIdx.x & 31) * 16;
    if(atomicAdd(&bar[leaf], 1) == 7){
      bar[leaf] = 0;
      __threadfence();
      if(atomicAdd(&bar[512], 1) == 31){
        bar[512] = 0;
        __threadfence();
        __atomic_store_n(gen, g + 1, __ATOMIC_RELEASE);
      }
    }
    while(__atomic_load_n(gen, __ATOMIC_ACQUIRE) == g){ __builtin_amdgcn_s_sleep(2); }
  }
  __syncthreads();
  __threadfence();                              // acquire: drop stale L1 before reading others' data
}

// ---------------- shared memory overlay ----------------
struct SMem {
  float Ul[ADIM*LDIM];   // persistent across scan
  float Fl[LDIM*31];
  union {
    float xr[E];                                              // prologue Vh
    float p1i[PDIM];                                          // prenet init
    struct { float cumh[48]; float loc[16*LDIM]; } ufa;       // Uf phase
    struct { float wsp[256], Ws[ADIM], vl[ADIM], el[T], red[256]; } att;
    struct { float lin[H+E], pp[160], outl[MDIM], p1[PDIM]; } prj;
  } u;
};

// ---------------- device bodies ----------------
template<bool F32>
__device__ void do_lstm_j(int j,
    const void* __restrict__ wih, const void* __restrict__ whh,
    const void* __restrict__ bih, const void* __restrict__ bhh,
    const float* __restrict__ in_x, const float* __restrict__ in_h,
    float* __restrict__ c_io, float* __restrict__ h_out)
{
  int lane = threadIdx.x & 63;
  int wv = threadIdx.x >> 6;
  float acc[4][4];
#pragma unroll
  for(int g=0;g<4;g++)
#pragma unroll
    for(int bb=0;bb<4;bb++) acc[g][bb]=0.f;

#pragma unroll
  for(int it=0; it<4; it++){
    int k = it*256 + lane*4;
    float xi[4][4];
#pragma unroll
    for(int bb=0;bb<4;bb++) __builtin_memcpy(xi[bb], &in_x[(size_t)(wv*4+bb)*H + k], 16);
#pragma unroll
    for(int g=0;g<4;g++){
      float w[4]; ld4<F32>(wih, ((size_t)(g*H + j))*H + k, w);
#pragma unroll
      for(int bb=0;bb<4;bb++)
        acc[g][bb] += w[0]*xi[bb][0] + w[1]*xi[bb][1] + w[2]*xi[bb][2] + w[3]*xi[bb][3];
    }
  }
#pragma unroll
  for(int it=0; it<4; it++){
    int k = it*256 + lane*4;
    float xi[4][4];
#pragma unroll
    for(int bb=0;bb<4;bb++) __builtin_memcpy(xi[bb], &in_h[(size_t)(wv*4+bb)*H + k], 16);
#pragma unroll
    for(int g=0;g<4;g++){
      float w[4]; ld4<F32>(whh, ((size_t)(g*H + j))*H + k, w);
#pragma unroll
      for(int bb=0;bb<4;bb++)
        acc[g][bb] += w[0]*xi[bb][0] + w[1]*xi[bb][1] + w[2]*xi[bb][2] + w[3]*xi[bb][3];
    }
  }
#pragma unroll
  for(int off=1; off<64; off<<=1){
#pragma unroll
    for(int g=0;g<4;g++)
#pragma unroll
      for(int bb=0;bb<4;bb++)
        acc[g][bb] += __shfl_xor(acc[g][bb], off, 64);
  }
  if(lane == 0){
    float bsum[4];
#pragma unroll
    for(int g=0;g<4;g++) bsum[g] = ld1<F32>(bih, g*H+j) + ld1<F32>(bhh, g*H+j);
#pragma unroll
    for(int bb=0;bb<4;bb++){
      int b = wv*4+bb;
      float zi = acc[0][bb] + bsum[0];
      float zf = acc[1][bb] + bsum[1];
      float zg = acc[2][bb] + bsum[2];
      float zo = acc[3][bb] + bsum[3];
      float ig = fast_sig(zi), fg = fast_sig(zf);
      float gg = fast_tanh(zg), og = fast_sig(zo);
      float c = fg * c_io[(size_t)b*H+j] + ig*gg;
      c_io[(size_t)b*H+j] = c;
      h_out[(size_t)b*H+j] = og * fast_tanh(c);
    }
  }
}

// Uf chunk: idx in [0,400): b = idx/25, 16 t-values. Requires sm.Ul/sm.Fl staged.
template<bool F32>
__device__ void do_uf(int idx, const float* __restrict__ cum, float* __restrict__ Uf, SMem& sm)
{
  int b = idx / 25, tc = idx % 25, t0 = tc*16;
  int tid = threadIdx.x;
  __syncthreads();
  if(tid < 46){ int g = t0 - 15 + tid; sm.u.ufa.cumh[tid] = (g>=0 && g<T) ? cum[b*T+g] : 0.f; }
  __syncthreads();
  for(int i=tid; i<16*LDIM; i+=256){
    int tl = i >> 5, l = i & 31;
    float s=0.f;
#pragma unroll
    for(int q=0;q<31;q++) s += sm.u.ufa.cumh[tl+q]*sm.Fl[l*31+q];
    sm.u.ufa.loc[i] = s;
  }
  __syncthreads();
  int tl = tid >> 4, al = tid & 15;
  int t = t0 + tl;
#pragma unroll
  for(int aa=0; aa<8; aa++){
    int a = al*8 + aa;
    float s=0.f;
#pragma unroll
    for(int l=0;l<LDIM;l++) s += sm.u.ufa.loc[tl*LDIM+l]*sm.Ul[a*LDIM+l];
    Uf[((size_t)b*T + t)*ADIM + a] = s;
  }
}

template<bool F32>
__device__ void do_att(int b, int t,
    const float* __restrict__ h1, float* __restrict__ att_w,
    float* __restrict__ lstm_in, float* __restrict__ cum,
    const float* __restrict__ Vh, const float* __restrict__ Uf,
    const void* __restrict__ x,
    const void* __restrict__ attW, const void* __restrict__ attWb, const void* __restrict__ attv,
    SMem& sm)
{
  int tid = threadIdx.x;
  auto& A = sm.u.att;
  {
    int a = tid >> 1, s = tid & 1;
    size_t base = (size_t)a*H + s*512;
    const float* hr = &h1[(size_t)b*H + s*512];
    float acc=0.f;
#pragma unroll 4
    for(int k=0;k<512;k+=4){
      float w[4]; ld4<F32>(attW, base+k, w);
      acc += w[0]*hr[k]+w[1]*hr[k+1]+w[2]*hr[k+2]+w[3]*hr[k+3];
    }
    A.wsp[tid]=acc;
  }
  __syncthreads();
  if(tid < ADIM){ A.Ws[tid] = A.wsp[2*tid]+A.wsp[2*tid+1] + ld1<F32>(attWb, tid); A.vl[tid] = ld1<F32>(attv, tid); }
  __syncthreads();
  for(int tt=tid; tt<T; tt+=256){
    const float* vh = &Vh[((size_t)b*T+tt)*ADIM];
    const float* uf = &Uf[((size_t)b*T+tt)*ADIM];
    float acc=0.f;
#pragma unroll 4
    for(int a=0;a<ADIM;a+=4){
      float v4[4], u4[4];
      __builtin_memcpy(v4, &vh[a], 16);
      __builtin_memcpy(u4, &uf[a], 16);
      acc += A.vl[a+0]*fast_tanh(A.Ws[a+0]+v4[0]+u4[0]);
      acc += A.vl[a+1]*fast_tanh(A.Ws[a+1]+v4[1]+u4[1]);
      acc += A.vl[a+2]*fast_tanh(A.Ws[a+2]+v4[2]+u4[2]);
      acc += A.vl[a+3]*fast_tanh(A.Ws[a+3]+v4[3]+u4[3]);
    }
    A.el[tt]=acc;
  }
  __syncthreads();
  float mx = -1e30f;
  for(int tt=tid; tt<T; tt+=256) mx = fmaxf(mx, A.el[tt]);
  A.red[tid]=mx; __syncthreads();
  for(int s=128;s>0;s>>=1){ if(tid<s) A.red[tid]=fmaxf(A.red[tid],A.red[tid+s]); __syncthreads(); }
  mx = A.red[0]; __syncthreads();
  float sum=0.f;
  for(int tt=tid; tt<T; tt+=256){ float ex=__expf(A.el[tt]-mx); A.el[tt]=ex; sum+=ex; }
  A.red[tid]=sum; __syncthreads();
  for(int s=128;s>0;s>>=1){ if(tid<s) A.red[tid]+=A.red[tid+s]; __syncthreads(); }
  float inv = 1.f/A.red[0];
  __syncthreads();
  for(int tt=tid; tt<T; tt+=256){ float aw = A.el[tt]*inv; A.el[tt]=aw; cum[b*T+tt] += aw; }
  __syncthreads();
  {
    float a0=0.f, a1=0.f, a2=0.f;
    const size_t xb = (size_t)b*T*E;
#pragma unroll 4
    for(int tt=0; tt<T; tt++){
      float aw = A.el[tt];
      size_t base = xb + (size_t)tt*E + tid;
      a0 += aw * ld1<F32>(x, base);
      a1 += aw * ld1<F32>(x, base+256);
      a2 += aw * ld1<F32>(x, base+512);
    }
    att_w[b*E + tid]       = a0;
    att_w[b*E + tid + 256] = a1;
    att_w[b*E + tid + 512] = a2;
    lstm_in[b*H + PDIM + tid]       = a0;
    lstm_in[b*H + PDIM + tid + 256] = a1;
    lstm_in[b*H + PDIM + tid + 512] = a2;
  }
}

template<bool F32>
__device__ void do_proj(int b, int t,
    const float* __restrict__ h1, const float* __restrict__ att_r,
    float* __restrict__ lstm_in,
    const void* __restrict__ projw, const void* __restrict__ projb,
    const void* __restrict__ pw1, const void* __restrict__ pb1,
    const void* __restrict__ pw2, const void* __restrict__ pb2,
    void* __restrict__ outp, SMem& sm)
{
  int tid = threadIdx.x;
  auto& Pr = sm.u.prj;
  for(int i=tid;i<H;i+=256) Pr.lin[i] = h1[(size_t)b*H+i];
  for(int i=tid;i<E;i+=256) Pr.lin[H+i] = att_r[b*E+i];
  __syncthreads();
  if(tid < 160){
    int m = tid >> 1, s = tid & 1;
    size_t base = (size_t)m*1792 + s*896;
    const float* lr = &Pr.lin[s*896];
    float acc=0.f;
#pragma unroll 4
    for(int k=0;k<896;k+=4){
      float w[4]; ld4<F32>(projw, base+k, w);
      acc += w[0]*lr[k]+w[1]*lr[k+1]+w[2]*lr[k+2]+w[3]*lr[k+3];
    }
    Pr.pp[tid]=acc;
  }
  __syncthreads();
  if(tid < MDIM){
    float o = Pr.pp[2*tid]+Pr.pp[2*tid+1] + ld1<F32>(projb, tid);
    Pr.outl[tid]=o;
    st1<F32>(outp, ((size_t)b*T + t)*MDIM + tid, o);
  }
  __syncthreads();
  {
    float acc = ld1<F32>(pb1, tid);
#pragma unroll
    for(int k=0;k<MDIM;k+=4){
      float w[4]; ld4<F32>(pw1, (size_t)tid*MDIM+k, w);
      acc += w[0]*Pr.outl[k]+w[1]*Pr.outl[k+1]+w[2]*Pr.outl[k+2]+w[3]*Pr.outl[k+3];
    }
    Pr.p1[tid] = fmaxf(acc,0.f);
  }
  __syncthreads();
  {
    float acc = ld1<F32>(pb2, tid);
#pragma unroll 4
    for(int k=0;k<PDIM;k+=4){
      float w[4]; ld4<F32>(pw2, (size_t)tid*PDIM+k, w);
      acc += w[0]*Pr.p1[k]+w[1]*Pr.p1[k+1]+w[2]*Pr.p1[k+2]+w[3]*Pr.p1[k+3];
    }
    lstm_in[b*H + tid] = fmaxf(acc,0.f);
  }
}

// ---------------- params ----------------
struct KP {
  const void *x, *pw1,*pb1,*pw2,*pb2;
  const void *wih0,*whh0,*bih0,*bhh0,*wih1,*whh1,*bih1,*bhh1;
  const void *attW,*attWb,*attV,*attU,*attF,*attv,*projw,*projb;
  const void *pnw2,*pnw3;
  float *Vh,*Uf,*h0a,*h0b,*h1a,*h1b,*c0,*c1,*att0,*att1,*lstm_in,*cum;
  u16 *wf2,*wf3;
  void* out;
  const int* dtf;
  float* state0;
  int* bar;
};

// ---------------- dtype detect + barrier init ----------------
__global__ void k_detect(const uint32_t* __restrict__ x, int* flag, int* bar){
  for(int i=threadIdx.x;i<NBAR;i+=256) bar[i] = 0;
  uint32_t w = x[threadIdx.x];
  float v = bf2f((u16)(w & 0xffffu));
  int bad = (fabsf(v) < 1e4f) ? 0 : 1;
  __shared__ int s[256];
  s[threadIdx.x] = bad;
  __syncthreads();
  for(int st=128; st>0; st>>=1){ if(threadIdx.x<st) s[threadIdx.x]+=s[threadIdx.x+st]; __syncthreads(); }
  if(threadIdx.x==0) *flag = (s[0] >= 8) ? 1 : 0;
}

// ---------------- persistent kernel (plain launch, software grid barrier) ----------------
template<bool F32>
__device__ void persist_body(const KP& P, SMem& sm){
  const int blk = blockIdx.x, tid = threadIdx.x;
  // phase 0: zero state
  for(int i = blk*256+tid; i < NZERO; i += GSZ*256) P.state0[i] = 0.f;
  gbar(P.bar);
  // prologue: stage Ul/Fl (persistent LDS), Vh, repack, prenet init
  for(int i=tid;i<ADIM*LDIM;i+=256) sm.Ul[i] = ld1<F32>(P.attU, i);
  for(int i=tid;i<LDIM*31;i+=256)  sm.Fl[i] = ld1<F32>(P.attF, i);
  for(int bt = blk; bt < B*T; bt += GSZ){
    __syncthreads();
    for(int i=tid;i<E;i+=256) sm.u.xr[i] = ld1<F32>(P.x, (size_t)bt*E+i);
    __syncthreads();
    if(tid < ADIM){
      float acc=0.f;
#pragma unroll 4
      for(int k=0;k<E;k+=4){
        float w[4]; ld4<F32>(P.attV, (size_t)tid*E+k, w);
        acc += w[0]*sm.u.xr[k]+w[1]*sm.u.xr[k+1]+w[2]*sm.u.xr[k+2]+w[3]*sm.u.xr[k+3];
      }
      P.Vh[(size_t)bt*ADIM + tid] = acc;
    }
  }
  for(int i = blk*256+tid; i < NRPK; i += GSZ*256){
    int jj = i & 7, lane = (i>>3) & 63, bq = i >> 9;
    int ot = bq & 15, ic = (bq >> 4) & 7, kw = bq >> 7;
    int o = ot*16 + (lane & 15);
    int i0 = ic*32 + (lane >> 4)*8;
    size_t s = ((size_t)o*256 + (i0+jj))*5 + kw;
    P.wf2[i] = f2bf(ld1<F32>(P.pnw2, s));
    P.wf3[i] = f2bf(ld1<F32>(P.pnw3, s));
  }
  if(blk == 0){
    __syncthreads();
    sm.u.p1i[tid] = fmaxf(ld1<F32>(P.pb1, tid), 0.f);
    __syncthreads();
    float acc = ld1<F32>(P.pb2, tid);
    for(int k=0;k<PDIM;k+=4){
      float w[4]; ld4<F32>(P.pw2, (size_t)tid*PDIM+k, w);
      acc += w[0]*sm.u.p1i[k]+w[1]*sm.u.p1i[k+1]+w[2]*sm.u.p1i[k+2]+w[3]*sm.u.p1i[k+3];
    }
    float p2 = fmaxf(acc, 0.f);
    for(int b=0;b<B;b++) P.lstm_in[b*H + tid] = p2;
  }
  gbar(P.bar);
  // scan
  for(int t=0; t<T; t++){
    const float* h0r = (t&1)? P.h0b : P.h0a;
    float*       h0w = (t&1)? P.h0a : P.h0b;
    const float* h1r = (t&1)? P.h1b : P.h1a;
    float*       h1w = (t&1)? P.h1a : P.h1b;
    const float* attr= (t&1)? P.att1 : P.att0;
    float*       attw= (t&1)? P.att0 : P.att1;
    // phase A: lstm0 (4 j/block) + Uf(this step)
#pragma unroll
    for(int jj=0;jj<4;jj++)
      do_lstm_j<F32>(4*blk+jj, P.wih0,P.whh0,P.bih0,P.bhh0, P.lstm_in, h0r, P.c0, h0w);
    do_uf<F32>(blk, P.cum, P.Uf, sm);
    if(blk < 144) do_uf<F32>(256+blk, P.cum, P.Uf, sm);
    gbar(P.bar);
    // phase B: lstm1
#pragma unroll
    for(int jj=0;jj<4;jj++)
      do_lstm_j<F32>(4*blk+jj, P.wih1,P.whh1,P.bih1,P.bhh1, h0w, h1r, P.c1, h1w);
    gbar(P.bar);
    // phase C: attention | proj/prenet
    if(blk < 16)
      do_att<F32>(blk, t, h1w, attw, P.lstm_in, P.cum, P.Vh, P.Uf, P.x,
                  P.attW, P.attWb, P.attv, sm);
    else if(blk < 32)
      do_proj<F32>(blk-16, t, h1w, attr, P.lstm_in, P.projw, P.projb,
                   P.pw1, P.pb1, P.pw2, P.pb2, P.out, sm);
    gbar(P.bar);
  }
}

__global__ __launch_bounds__(256, 2) void k_persist(KP P){
  __shared__ SMem sm;
  if(*P.dtf) persist_body<true>(P, sm);
  else       persist_body<false>(P, sm);
}

// ------------- fused PostNet: one block per (b,t); mel lives in d_out -------------
template<bool F32>
__device__ void postnet_body(
    const void* __restrict__ w1, const void* __restrict__ b1,
    const u16* __restrict__ wf2, const void* __restrict__ b2,
    const u16* __restrict__ wf3, const void* __restrict__ b3,
    const void* __restrict__ w4, const void* __restrict__ b4,
    void* __restrict__ out)
{
  __shared__ u16 YT[88*264];
  __shared__ float mell[84];
  __shared__ float w4l[256*5];
  __shared__ float red4[160];
  int bt = blockIdx.x;
  int tid = threadIdx.x;
  if(tid < 84) mell[tid] = (tid>=2 && tid<82) ? ld1<F32>(out, (size_t)bt*MDIM + tid-2) : 0.f;
  for(int i=tid;i<256*5;i+=256) w4l[i] = ld1<F32>(w4, i);
  for(int i=tid;i<4*264;i+=256){
    int r = i/264, c = i - r*264;
    int row = (r<2)? r : 80+r;
    YT[row*264 + c] = 0;
  }
  __syncthreads();
  {
    float wr[5];
#pragma unroll
    for(int q=0;q<5;q++) wr[q] = ld1<F32>(w1, tid*5+q);
    float bb = ld1<F32>(b1, tid);
    for(int m=0;m<MDIM;m++){
      float s = bb;
#pragma unroll
      for(int q=0;q<5;q++) s += wr[q]*mell[m+q];
      YT[(m+2)*264 + tid] = f2bf(fast_tanh(s));
    }
  }
  __syncthreads();
  int lane = tid & 63, wv = tid >> 6;
  int lr = lane & 15, quad = lane >> 4;
  const u16* WF[2] = {wf2, wf3};
  const void* BS[2] = {b2, b3};
#pragma unroll 1
  for(int layer=0; layer<2; layer++){
    float4v acc[4][5];
#pragma unroll
    for(int ot=0;ot<4;ot++){
      int ob = (wv*4+ot)*16 + quad*4;
#pragma unroll
      for(int mt=0;mt<5;mt++)
#pragma unroll
        for(int r=0;r<4;r++) acc[ot][mt][r] = ld1<F32>(BS[layer], ob + r);
    }
    const u16* wf = WF[layer];
    for(int kw=0;kw<5;kw++){
      for(int ic=0;ic<8;ic++){
        short8v a[4];
#pragma unroll
        for(int ot=0;ot<4;ot++){
          size_t idx = ((size_t)(kw*128 + ic*16 + (wv*4+ot))*64 + lane)*8;
          __builtin_memcpy(&a[ot], &wf[idx], 16);
        }
        short8v bfr[5];
        int ib = ic*32 + quad*8;
#pragma unroll
        for(int mt=0;mt<5;mt++){
          int row = mt*16 + lr + kw;
          __builtin_memcpy(&bfr[mt], &YT[row*264 + ib], 16);
        }
#pragma unroll
        for(int ot=0;ot<4;ot++)
#pragma unroll
          for(int mt=0;mt<5;mt++)
            acc[ot][mt] = __builtin_amdgcn_mfma_f32_16x16x32_bf16(a[ot], bfr[mt], acc[ot][mt], 0,0,0);
      }
    }
    __syncthreads();
#pragma unroll
    for(int ot=0;ot<4;ot++){
      int ob = (wv*4+ot)*16 + quad*4;
#pragma unroll
      for(int mt=0;mt<5;mt++){
        int row = mt*16 + lr + 2;
        u16 pk[4];
#pragma unroll
        for(int r=0;r<4;r++) pk[r] = f2bf(fast_tanh(acc[ot][mt][r]));
        __builtin_memcpy(&YT[row*264 + ob], pk, 8);
      }
    }
    __syncthreads();
  }
  if(tid < 160){
    int m = tid >> 1, s = tid & 1;
    float accv = 0.f;
    for(int i = s*128; i < s*128+128; i++){
#pragma unroll
      for(int q=0;q<5;q++) accv += w4l[i*5+q] * bf2f(YT[(m+q)*264 + i]);
    }
    red4[tid] = accv;
  }
  __syncthreads();
  if(tid < MDIM){
    float o = red4[2*tid] + red4[2*tid+1] + ld1<F32>(b4, 0) + mell[tid+2];
    st1<F32>(out, (size_t)bt*MDIM + tid, o);
  }
}
__global__ __launch_bounds__(256) void k_postnet(
    const void* w1, const void* b1, const u16* wf2, const void* b2,
    const u16* wf3, const void* b3, const void* w4, const void* b4,
    void* out, const int* dtf)
{
  if(*dtf) postnet_body<true>(w1,b1,wf2,b2,wf3,b3,w4,b4,out);
  else     postnet_body<false>(w1,b1,wf2,b2,wf3,b3,w4,b4,out);
}

extern "C" void kernel_launch(void* const* d_in, const int* in_sizes, int n_in,
                              void* d_out, int out_size, void* d_ws, size_t ws_size,
                              hipStream_t stream)
{
  (void)in_sizes; (void)n_in; (void)out_size; (void)ws_size;
  KP P;
  P.x    = d_in[0];
  P.pw1  = d_in[1];  P.pb1 = d_in[2];
  P.pw2  = d_in[3];  P.pb2 = d_in[4];
  P.wih0 = d_in[5];  P.whh0 = d_in[6];  P.bih0 = d_in[7];  P.bhh0 = d_in[8];
  P.wih1 = d_in[9];  P.whh1 = d_in[10]; P.bih1 = d_in[11]; P.bhh1 = d_in[12];
  P.attW = d_in[13]; P.attWb= d_in[14];
  P.attV = d_in[15]; P.attU = d_in[16]; P.attF = d_in[17]; P.attv = d_in[18];
  P.projw= d_in[19]; P.projb= d_in[20];
  const void* pnw1 = d_in[23]; const void* pnb1 = d_in[24];
  P.pnw2 = d_in[25]; const void* pnb2 = d_in[26];
  P.pnw3 = d_in[27]; const void* pnb3 = d_in[28];
  const void* pnw4 = d_in[29]; const void* pnb4 = d_in[30];
  P.out  = d_out;

  float* base = (float*)d_ws;
  size_t off = 4;
  int* dtf = (int*)d_ws;
  P.dtf = dtf;
  P.Vh   = base + off; off += (size_t)B*T*ADIM;
  P.Uf   = base + off; off += (size_t)B*T*ADIM;
  P.h0a  = base + off; off += B*H;
  P.h0b  = base + off; off += B*H;
  P.h1a  = base + off; off += B*H;
  P.h1b  = base + off; off += B*H;
  P.c0   = base + off; off += B*H;
  P.c1   = base + off; off += B*H;
  P.att0 = base + off; off += B*E;
  P.att1 = base + off; off += B*E;
  P.lstm_in = base + off; off += B*H;
  P.cum  = base + off; off += B*T;
  P.wf2 = (u16*)(base + off); off += NRPK/2;
  P.wf3 = (u16*)(base + off); off += NRPK/2;
  P.bar = (int*)(base + off); off += NBAR;
  P.state0 = P.h0a;

  k_detect<<<1, 256, 0, stream>>>((const uint32_t*)P.x, dtf, P.bar);
  k_persist<<<GSZ, 256, 0, stream>>>(P);
  k_postnet<<<B*T, 256, 0, stream>>>(pnw1, pnb1, P.wf2, pnb2, P.wf3, pnb3,
                                     pnw4, pnb4, d_out, dtf);
}